// Round 2
// baseline (265.858 us; speedup 1.0000x reference)
//
#include <hip/hip_runtime.h>

typedef _Float16 half_t;
typedef _Float16 half8 __attribute__((ext_vector_type(8)));
typedef _Float16 half4 __attribute__((ext_vector_type(4)));
typedef _Float16 half2v __attribute__((ext_vector_type(2)));
typedef float f32x4 __attribute__((ext_vector_type(4)));

#define NELEM 16384
#define SROW 168   // LDS row stride in halves (dword stride 84 == 20 mod 32)
#define NROWS 40   // real rows only; pad rows 40..47 eliminated

// ---------------------------------------------------------------------------
// In-wave fused network. One wave per BLOCK (64 threads), 2 elements per wave.
// Barrier-free: the wave owns a private 40x168 fp16 LDS buffer; LDS shrunk
// from 48 to 40 rows so 11 blocks (11 waves) fit per CU (was 8 waves/CU).
// Tile-2 MFMA fragment reads that would touch pad rows 40..47 are clamped
// in-bounds (junk feeds only discarded D rows); tile-2 stores are guarded.
//   B (weights): global pre-swizzled frags [ks][nt][lane][8] (fp16).
//   Layouts (verified): A[m=lane&15][k=quad*8+j], B[k][n=lane&15],
//                       D[row=quad*4+r][col=lane&15].
// ---------------------------------------------------------------------------

template<int KS, int MT>
__device__ __forceinline__ void load_af(half8 (&af)[KS][MT], const half_t* S, int m, int q) {
    #pragma unroll
    for (int t = 0; t < MT; ++t) {
        int r = t*16 + m;
        if (t == 2 && r >= NROWS) r -= 16;   // clamp pad-row reads in-bounds (D rows discarded)
        const half_t* Sp = S + r*SROW + q*8;
        #pragma unroll
        for (int ks = 0; ks < KS; ++ks)
            af[ks][t] = *(const half8*)(Sp + ks*32);
    }
}

// EPI: 0 = f16 store cols [0,NT*16) (pad cols get 0);  1 = f16 store at col
// offset 112, col<56 (the f vector);  2 = logits -> lbufw[row] (m==0);
// 3 = gp -> gpb[row*112+col] fp32, row<2.   INIT==1: add gpb[e*112+col].
// All row-stores guarded to row<40 when MT==3 (t==2 && q>=2 skipped).
template<int KS, int MT, int NT, int C, int EPI, int INIT, bool RELU>
__device__ __forceinline__ void run_layer(
    const half8 (&af)[KS][MT], half_t* S,
    const half_t* __restrict__ wf, const float* __restrict__ bias,
    float* gpb, float* lbufw, float extra, int lane)
{
    const int m = lane & 15, q = lane >> 4;
    #pragma unroll
    for (int nt = 0; nt < NT; ++nt) {
        const int col = nt*16 + m;
        half8 bh[KS];
        #pragma unroll
        for (int ks = 0; ks < KS; ++ks)
            bh[ks] = *(const half8*)(wf + ((size_t)(ks*NT + nt)*64 + lane)*8);
        f32x4 acc[MT];
        #pragma unroll
        for (int t = 0; t < MT; ++t) acc[t] = f32x4{0.f,0.f,0.f,0.f};
        #pragma unroll
        for (int ks = 0; ks < KS; ++ks)
            #pragma unroll
            for (int t = 0; t < MT; ++t)
                acc[t] = __builtin_amdgcn_mfma_f32_16x16x32_f16(af[ks][t], bh[ks], acc[t], 0,0,0);
        float bv = 0.f;
        if (EPI == 0 || EPI == 1) bv = (col < C) ? bias[col] : 0.f;
        #pragma unroll
        for (int t = 0; t < MT; ++t) {
            const bool rowok = (MT < 3) || (t < 2) || (q < 2);
            #pragma unroll
            for (int r = 0; r < 4; ++r) {
                const int row = t*16 + q*4 + r;
                float v = acc[t][r] + bv;
                if constexpr (INIT == 1) {
                    // e = row>=20, resolved per compile-time t (MT==3 only)
                    const int eoff = (t == 0) ? 0 : ((t == 2) ? 112 : ((q == 0) ? 0 : 112));
                    v += gpb[eoff + col];
                }
                if (RELU) v = fmaxf(v, 0.f);
                if (EPI == 0) {
                    if (rowok) S[row*SROW + col] = (half_t)v;
                } else if (EPI == 1) {
                    if (rowok && col < 56) S[row*SROW + 112 + col] = (half_t)v;
                } else if (EPI == 2) {
                    if (rowok && m == 0) lbufw[row] = v + extra;
                } else if (EPI == 3) {
                    if (row < 2) gpb[row*112 + col] = v;
                }
            }
        }
    }
}

// ---------------------------------------------------------------------------
// Prep: build fp16 weight fragments in ws. One 16x32 tile per block.
// ---------------------------------------------------------------------------
struct PrepDesc { const float* w; half_t* out; int K, C, KS, NT, toff; };
struct PrepArgs { PrepDesc d[11]; };

__global__ __launch_bounds__(64) void k_prep(PrepArgs a) {
    const int blk = blockIdx.x, lane = threadIdx.x;
    int li = 0;
    #pragma unroll
    for (int i = 1; i < 11; ++i) if (blk >= a.d[i].toff) li = i;
    const PrepDesc d = a.d[li];
    const int t = blk - d.toff;
    const int ks = t / d.NT, nt = t - (t / d.NT) * d.NT;
    const int c = nt*16 + (lane & 15);
    half_t* o = d.out + ((size_t)(ks*d.NT + nt))*512 + lane*8;
    half8 hv;
    #pragma unroll
    for (int j = 0; j < 8; ++j) {
        const int k = ks*32 + (lane >> 4)*8 + j;
        float v = (k < d.K && c < d.C) ? d.w[(size_t)k*d.C + c] : 0.f;
        hv[j] = (half_t)v;
    }
    *(half8*)o = hv;
}

// ---------------------------------------------------------------------------
// k_main: 64 threads = 1 wave, 2 elements. Barrier-free. 11 blocks/CU.
// ---------------------------------------------------------------------------
__global__ __launch_bounds__(64, 4) void k_main(
    const float* __restrict__ state,
    const half_t* __restrict__ wfrag,
    const float* __restrict__ m1b0, const float* __restrict__ m1b1,
    const float* __restrict__ m2b0, const float* __restrict__ m2b1,
    const float* __restrict__ ab0, const float* __restrict__ ab1,
    const float* __restrict__ ab2,
    const float* __restrict__ m3b0, const float* __restrict__ m3b1,
    const float* __restrict__ m3b2,
    const float* __restrict__ m3w3, const float* __restrict__ m3b3,
    float* __restrict__ out)
{
    __shared__ __align__(16) half_t S[NROWS*SROW];
    __shared__ float gpb[2*112];
    __shared__ float lbufw[NROWS];

    const int lane = threadIdx.x;
    const int m = lane & 15, q = lane >> 4;
    const int ebase = blockIdx.x * 2;

    const half_t* wfL0 = wfrag;
    const half_t* wfL1 = wfL0 + 5120;
    const half_t* wfL2 = wfL1 + 17920;
    const half_t* wfL3 = wfL2 + 14336;
    const half_t* wfL4 = wfL3 + 8192;
    const half_t* wfL5 = wfL4 + 14336;
    const half_t* wfL6 = wfL5 + 14336;
    const half_t* wfL7 = wfL6 + 14336;
    const half_t* wfL8 = wfL7 + 2048;
    const half_t* wfL9 = wfL8 + 10240;
    const half_t* wfL10 = wfL9 + 17920;

    // ---- stage x: rows 0..39 x cols 0..32 (zero K-pad cols 13..31)
    {
        const float* xg = state + (size_t)ebase * 20 * 13;
        #pragma unroll
        for (int z = 0; z < 20; ++z) {
            const int u = z*64 + lane;
            const int r = u >> 5, c = u & 31;
            float v = (c < 13) ? xg[r*13 + c] : 0.f;
            S[r*SROW + c] = (half_t)v;
        }
    }

    // ---- L0: h1 = relu(x @ m1w0 + b), in-place (x -> cols 0..160)
    {
        half8 af[1][3]; load_af<1,3>(af, S, m, q);
        run_layer<1,3,10,150,0,0,true>(af, S, wfL0, m1b0, gpb, lbufw, 0.f, lane);
    }
    // ---- L1: h = relu(h1 @ m1w1 + b)  (cols 0..112)
    {
        half8 af[5][3]; load_af<5,3>(af, S, m, q);
        run_layer<5,3,7,100,0,0,true>(af, S, wfL1, m1b1, gpb, lbufw, 0.f, lane);
    }
    // ---- keep h fragments in registers (serves L2 and L4)
    half8 hf[4][3]; load_af<4,3>(hf, S, m, q);

    // ---- g = mean_n h -> strips at cols 112..168 rows {2e, 2e+1}; vectorized
    {
        const int ge = (lane >= 25) ? 1 : 0;
        const int gc = (lane - ge*25) * 4;          // col group base, 0..96
        if (lane < 50) {
            f32x4 s = {0.f,0.f,0.f,0.f};
            #pragma unroll
            for (int n = 0; n < 20; ++n) {
                half4 hv = *(const half4*)(S + (ge*20+n)*SROW + gc);
                s[0] += (float)hv[0]; s[1] += (float)hv[1];
                s[2] += (float)hv[2]; s[3] += (float)hv[3];
            }
            const int st = (gc >= 56) ? 1 : 0;
            half4 g4;
            g4[0] = (half_t)(s[0]*0.05f); g4[1] = (half_t)(s[1]*0.05f);
            g4[2] = (half_t)(s[2]*0.05f); g4[3] = (half_t)(s[3]*0.05f);
            *(half4*)(S + (2*ge+st)*SROW + 112 + (gc - st*56)) = g4;
        } else if (lane < 56) {
            // zero strip1 tail positions 44..55 (k-pad region gaf will read)
            const int u2 = lane - 50;               // 0..5
            const int le = (u2 >= 3) ? 1 : 0, lp = u2 - le*3;
            const half4 z4 = {};
            *(half4*)(S + (2*le+1)*SROW + 112 + 44 + lp*4) = z4;
        }
    }
    // ---- gp = g @ aw0[100:]  (16-row tile; rows>=2 junk, discarded by guard)
    {
        half8 gaf[4][1];
        #pragma unroll
        for (int ks = 0; ks < 4; ++ks) {
            const int c = q*8 + ks*32;
            const int s = (c >= 112) ? 2 : (c >= 56 ? 1 : 0);
            gaf[ks][0] = *(const half8*)(S + (2*m + s)*SROW + 112 + (c - s*56));
        }
        run_layer<4,1,7,100,3,0,false>(gaf, S, wfL5, nullptr, gpb, lbufw, 0.f, lane);
    }
    // ---- L2: fh = relu(h @ m2w0 + b)  (h from regs; cols 0..112 overwritten)
    run_layer<4,3,7,100,0,0,true>(hf, S, wfL2, m2b0, gpb, lbufw, 0.f, lane);
    // ---- L3: f = fh @ m2w1 + b  -> cols 112..168 (f16, no relu)
    {
        half8 af[4][3]; load_af<4,3>(af, S, m, q);
        run_layer<4,3,4,50,1,0,false>(af, S, wfL3, m2b1, gpb, lbufw, 0.f, lane);
    }
    // ---- L4: a1 = relu(h @ aw0[:100] + gp + ab0)  (h from regs; cols 0..112)
    run_layer<4,3,7,100,0,1,true>(hf, S, wfL4, ab0, gpb, lbufw, 0.f, lane);
    // ---- L6: a2 = relu(a1 @ aw1 + ab1)  in-place
    {
        half8 af[4][3]; load_af<4,3>(af, S, m, q);
        run_layer<4,3,7,100,0,0,true>(af, S, wfL6, ab1, gpb, lbufw, 0.f, lane);
    }
    // ---- L7: logits = a2 @ aw2 + ab2 -> lbufw
    {
        half8 af[4][3]; load_af<4,3>(af, S, m, q);
        run_layer<4,3,1,1,2,0,false>(af, S, wfL7, nullptr, gpb, lbufw, ab2[0], lane);
    }
    // ---- weighted + self -> joint tile (rows 0..15, cols 0..64) ----
    {
        f32x4 wacc = {0.f,0.f,0.f,0.f};
        const int we = (lane >= 13) ? 1 : 0;
        const int wj = (lane - we*13) * 4;          // 0..48
        if (lane < 26) {
            #pragma unroll
            for (int n = 0; n < 20; ++n) {
                half4 f4 = *(const half4*)(S + (we*20+n)*SROW + 112 + wj);
                const float a = lbufw[we*20 + n];
                wacc[0] += (float)f4[0] * a;
                wacc[1] += (float)f4[1] * a;
                wacc[2] += (float)f4[2] * a;
                wacc[3] += (float)f4[3] * a;
            }
        }
        float sv = 0.f;
        const int su = lane - 32;
        const int se = (su >= 6) ? 1 : 0, sd = su - se*6;
        if (lane >= 32 && lane < 44)
            sv = state[(size_t)(ebase + se)*260 + sd];
        // zero joint tile rows 0..15 cols 0..63 (b128)
        const half8 z8 = {};
        #pragma unroll
        for (int z = 0; z < 2; ++z) {
            const int u = z*64 + lane;
            *(half8*)(S + (u >> 3)*SROW + (u & 7)*8) = z8;
        }
        if (lane < 26) {
            half2v p0, p1;
            p0[0] = (half_t)wacc[0]; p0[1] = (half_t)wacc[1];
            p1[0] = (half_t)wacc[2]; p1[1] = (half_t)wacc[3];
            *(half2v*)(S + we*SROW + 6 + wj) = p0;
            *(half2v*)(S + we*SROW + 6 + wj + 2) = p1;
        }
        if (lane >= 32 && lane < 44)
            S[se*SROW + sd] = (half_t)sv;
    }
    // ---- head: v1 = relu(joint @ m3w0 + b0)  (rows 0..15, cols 0..160)
    {
        half8 af[2][1]; load_af<2,1>(af, S, m, q);
        run_layer<2,1,10,150,0,0,true>(af, S, wfL8, m3b0, gpb, lbufw, 0.f, lane);
    }
    // ---- v2 = relu(v1 @ m3w1 + b1)
    {
        half8 af[5][1]; load_af<5,1>(af, S, m, q);
        run_layer<5,1,7,100,0,0,true>(af, S, wfL9, m3b1, gpb, lbufw, 0.f, lane);
    }
    // ---- v3 = relu(v2 @ m3w2 + b2)
    {
        half8 af[4][1]; load_af<4,1>(af, S, m, q);
        run_layer<4,1,7,100,0,0,true>(af, S, wfL10, m3b2, gpb, lbufw, 0.f, lane);
    }
    // ---- out[e] = v3[e] . m3w3 + b3   (lanes 0-31 -> elem 0, 32-63 -> elem 1)
    {
        const int e = lane >> 5, k = lane & 31;
        const half_t* vr = S + e*SROW;
        float s = (float)vr[k]      * m3w3[k]
                + (float)vr[k + 32] * m3w3[k + 32]
                + (float)vr[k + 64] * m3w3[k + 64];
        if (k < 4) s += (float)vr[k + 96] * m3w3[k + 96];
        #pragma unroll
        for (int off = 16; off > 0; off >>= 1)
            s += __shfl_down(s, off, 32);
        if (k == 0) out[ebase + e] = s + m3b3[0];
    }
}

extern "C" void kernel_launch(void* const* d_in, const int* in_sizes, int n_in,
                              void* d_out, int out_size, void* d_ws, size_t ws_size,
                              hipStream_t stream) {
    const float* state = (const float*)d_in[0];
    const float* m1w0 = (const float*)d_in[1];
    const float* m1b0 = (const float*)d_in[2];
    const float* m1w1 = (const float*)d_in[3];
    const float* m1b1 = (const float*)d_in[4];
    const float* m2w0 = (const float*)d_in[5];
    const float* m2b0 = (const float*)d_in[6];
    const float* m2w1 = (const float*)d_in[7];
    const float* m2b1 = (const float*)d_in[8];
    const float* aw0  = (const float*)d_in[9];
    const float* ab0  = (const float*)d_in[10];
    const float* aw1  = (const float*)d_in[11];
    const float* ab1  = (const float*)d_in[12];
    const float* aw2  = (const float*)d_in[13];
    const float* ab2  = (const float*)d_in[14];
    const float* m3w0 = (const float*)d_in[15];
    const float* m3b0 = (const float*)d_in[16];
    const float* m3w1 = (const float*)d_in[17];
    const float* m3b1 = (const float*)d_in[18];
    const float* m3w2 = (const float*)d_in[19];
    const float* m3b2 = (const float*)d_in[20];
    const float* m3w3 = (const float*)d_in[21];
    const float* m3b3 = (const float*)d_in[22];

    half_t* wfrag = (half_t*)d_ws;   // 266,240 B of fragments

    PrepArgs pa;
    int off = 0; size_t hoff = 0; int idx = 0;
    auto add = [&](const float* w, int K, int C, int KS, int NT) {
        pa.d[idx] = PrepDesc{w, wfrag + hoff, K, C, KS, NT, off};
        off += KS*NT;
        hoff += (size_t)KS*NT*512;
        ++idx;
    };
    add(m1w0, 13, 150, 1, 10);          // L0
    add(m1w1, 150, 100, 5, 7);          // L1
    add(m2w0, 100, 100, 4, 7);          // L2
    add(m2w1, 100, 50, 4, 4);           // L3
    add(aw0, 100, 100, 4, 7);           // L4 (rows 0..99)
    add(aw0 + 100*100, 100, 100, 4, 7); // L5 (rows 100..199)
    add(aw1, 100, 100, 4, 7);           // L6
    add(aw2, 100, 1, 4, 1);             // L7
    add(m3w0, 56, 150, 2, 10);          // L8
    add(m3w1, 150, 100, 5, 7);          // L9
    add(m3w2, 100, 100, 4, 7);          // L10

    k_prep<<<off, 64, 0, stream>>>(pa);

    k_main<<<NELEM/2, 64, 0, stream>>>(state, wfrag,
        m1b0, m1b1, m2b0, m2b1, ab0, ab1, ab2,
        m3b0, m3b1, m3b2, m3w3, m3b3, (float*)d_out);
}

// Round 3
// 234.598 us; speedup vs baseline: 1.1333x; 1.1333x over previous
//
#include <hip/hip_runtime.h>

typedef _Float16 half_t;
typedef _Float16 half8 __attribute__((ext_vector_type(8)));
typedef _Float16 half4 __attribute__((ext_vector_type(4)));
typedef _Float16 half2v __attribute__((ext_vector_type(2)));
typedef float f32x4 __attribute__((ext_vector_type(4)));

#define NELEM 16384
#define SROW 168   // LDS row stride in halves (dword stride 84 == 20 mod 32)

// ---------------------------------------------------------------------------
// In-wave fused network. Wave = 2 elements (40 rows -> 3 M-tiles of 16).
// 4 waves/block, each owns a private 48x168 fp16 LDS slice; no data sharing.
// Raw s_barrier between layers keeps the 4 waves PHASE-LOCKED so their weight-
// fragment streams alias in L1 (the r2 experiment showed desynchronized waves
// each pay L2 latency on the 266KB/wave fragment stream).
//   B (weights): global pre-swizzled frags [ks][nt][lane][8] (fp16).
//   Layouts (verified): A[m=lane&15][k=quad*8+j], B[k][n=lane&15],
//                       D[row=quad*4+r][col=lane&15].
// ---------------------------------------------------------------------------

template<int KS, int MT>
__device__ __forceinline__ void load_af(half8 (&af)[KS][MT], const half_t* S, int m, int q) {
    #pragma unroll
    for (int ks = 0; ks < KS; ++ks)
        #pragma unroll
        for (int t = 0; t < MT; ++t)
            af[ks][t] = *(const half8*)(S + (t*16 + m)*SROW + q*8 + ks*32);
}

// EPI: 0 = f16 store cols [0,NT*16) (pad cols get 0);  1 = f16 store at col
// offset 112, col<56 (the f vector);  2 = logits -> lbufw[row] (m==0);
// 3 = gp -> gpb[row*112+col] fp32, row<2.   INIT==1: add gpb[e*112+col].
template<int KS, int MT, int NT, int C, int EPI, int INIT, bool RELU>
__device__ __forceinline__ void run_layer(
    const half8 (&af)[KS][MT], half_t* S,
    const half_t* __restrict__ wf, const float* __restrict__ bias,
    float* gpb, float* lbufw, float extra, int lane)
{
    const int m = lane & 15, q = lane >> 4;
    #pragma unroll
    for (int nt = 0; nt < NT; ++nt) {
        const int col = nt*16 + m;
        half8 bh[KS];
        #pragma unroll
        for (int ks = 0; ks < KS; ++ks)
            bh[ks] = *(const half8*)(wf + ((size_t)(ks*NT + nt)*64 + lane)*8);
        f32x4 acc[MT];
        #pragma unroll
        for (int t = 0; t < MT; ++t) acc[t] = f32x4{0.f,0.f,0.f,0.f};
        #pragma unroll
        for (int ks = 0; ks < KS; ++ks)
            #pragma unroll
            for (int t = 0; t < MT; ++t)
                acc[t] = __builtin_amdgcn_mfma_f32_16x16x32_f16(af[ks][t], bh[ks], acc[t], 0,0,0);
        float bv = 0.f;
        if (EPI == 0 || EPI == 1) bv = (col < C) ? bias[col] : 0.f;
        #pragma unroll
        for (int t = 0; t < MT; ++t) {
            #pragma unroll
            for (int r = 0; r < 4; ++r) {
                const int row = t*16 + q*4 + r;
                float v = acc[t][r] + bv;
                if constexpr (INIT == 1) {
                    // e = row/20 resolved per compile-time t (+q for t==1)
                    const int eoff = (t == 0) ? 0 : ((t == 2) ? 112 : ((q == 0) ? 0 : 112));
                    v += gpb[eoff + col];
                }
                if (RELU) v = fmaxf(v, 0.f);
                if (EPI == 0) {
                    S[row*SROW + col] = (half_t)v;
                } else if (EPI == 1) {
                    if (col < 56) S[row*SROW + 112 + col] = (half_t)v;
                } else if (EPI == 2) {
                    if (m == 0) lbufw[row] = v + extra;
                } else if (EPI == 3) {
                    if (row < 2) gpb[row*112 + col] = v;
                }
            }
        }
    }
}

// ---------------------------------------------------------------------------
// Prep: build fp16 weight fragments in ws. One 16x32 tile per block.
// ---------------------------------------------------------------------------
struct PrepDesc { const float* w; half_t* out; int K, C, KS, NT, toff; };
struct PrepArgs { PrepDesc d[11]; };

__global__ __launch_bounds__(64) void k_prep(PrepArgs a) {
    const int blk = blockIdx.x, lane = threadIdx.x;
    int li = 0;
    #pragma unroll
    for (int i = 1; i < 11; ++i) if (blk >= a.d[i].toff) li = i;
    const PrepDesc d = a.d[li];
    const int t = blk - d.toff;
    const int ks = t / d.NT, nt = t - (t / d.NT) * d.NT;
    const int c = nt*16 + (lane & 15);
    half_t* o = d.out + ((size_t)(ks*d.NT + nt))*512 + lane*8;
    half8 hv;
    #pragma unroll
    for (int j = 0; j < 8; ++j) {
        const int k = ks*32 + (lane >> 4)*8 + j;
        float v = (k < d.K && c < d.C) ? d.w[(size_t)k*d.C + c] : 0.f;
        hv[j] = (half_t)v;
    }
    *(half8*)o = hv;
}

// ---------------------------------------------------------------------------
// k_main: 256 threads = 4 waves, 2 elements each; per-layer phase-lock.
// ---------------------------------------------------------------------------
__global__ __launch_bounds__(256, 2) void k_main(
    const float* __restrict__ state,
    const half_t* __restrict__ wfrag,
    const float* __restrict__ m1b0, const float* __restrict__ m1b1,
    const float* __restrict__ m2b0, const float* __restrict__ m2b1,
    const float* __restrict__ ab0, const float* __restrict__ ab1,
    const float* __restrict__ ab2,
    const float* __restrict__ m3b0, const float* __restrict__ m3b1,
    const float* __restrict__ m3b2,
    const float* __restrict__ m3w3, const float* __restrict__ m3b3,
    float* __restrict__ out)
{
    __shared__ __align__(16) half_t S_all[4][48*SROW];
    __shared__ float gp_all[4][2*112];
    __shared__ float lb_all[4][48];

    const int tid = threadIdx.x;
    const int wv = tid >> 6, lane = tid & 63;
    const int m = lane & 15, q = lane >> 4;
    half_t* S = S_all[wv];
    float* gpb = gp_all[wv];
    float* lbufw = lb_all[wv];
    const int ebase = blockIdx.x * 8 + wv * 2;

    const half_t* wfL0 = wfrag;
    const half_t* wfL1 = wfL0 + 5120;
    const half_t* wfL2 = wfL1 + 17920;
    const half_t* wfL3 = wfL2 + 14336;
    const half_t* wfL4 = wfL3 + 8192;
    const half_t* wfL5 = wfL4 + 14336;
    const half_t* wfL6 = wfL5 + 14336;
    const half_t* wfL7 = wfL6 + 14336;
    const half_t* wfL8 = wfL7 + 2048;
    const half_t* wfL9 = wfL8 + 10240;
    const half_t* wfL10 = wfL9 + 17920;

    // ---- stage x: rows 0..39 x cols 0..31 (zero K-pad cols 13..31);
    //      vector-zero pad rows 40..47 (keeps L0 pad-row outputs deterministic)
    {
        const float* xg = state + (size_t)ebase * 20 * 13;
        #pragma unroll
        for (int z = 0; z < 20; ++z) {
            const int u = z*64 + lane;
            const int r = u >> 5, c = u & 31;
            float v = (c < 13) ? xg[r*13 + c] : 0.f;
            S[r*SROW + c] = (half_t)v;
        }
        if (lane < 32) {
            const int r = 40 + (lane >> 2), cg = (lane & 3)*8;
            *(half8*)(S + r*SROW + cg) = half8{};
        }
    }
    __builtin_amdgcn_s_barrier();

    // ---- L0: h1 = relu(x @ m1w0 + b), in-place (x -> cols 0..160)
    {
        half8 af[1][3]; load_af<1,3>(af, S, m, q);
        run_layer<1,3,10,150,0,0,true>(af, S, wfL0, m1b0, gpb, lbufw, 0.f, lane);
    }
    __builtin_amdgcn_s_barrier();
    // ---- L1: h = relu(h1 @ m1w1 + b)  (cols 0..112)
    {
        half8 af[5][3]; load_af<5,3>(af, S, m, q);
        run_layer<5,3,7,100,0,0,true>(af, S, wfL1, m1b1, gpb, lbufw, 0.f, lane);
    }
    __builtin_amdgcn_s_barrier();
    // ---- keep h fragments in registers (serves L2 and L4)
    half8 hf[4][3]; load_af<4,3>(hf, S, m, q);

    // ---- g = mean_n h -> strips at cols 112..168 rows {2e,2e+1}; vectorized
    {
        const int ge = (lane >= 25) ? 1 : 0;
        const int gc = (lane - ge*25) * 4;          // col group base, 0..96
        if (lane < 50) {
            f32x4 s = {0.f,0.f,0.f,0.f};
            #pragma unroll
            for (int n = 0; n < 20; ++n) {
                half4 hv = *(const half4*)(S + (ge*20+n)*SROW + gc);
                s[0] += (float)hv[0]; s[1] += (float)hv[1];
                s[2] += (float)hv[2]; s[3] += (float)hv[3];
            }
            const int st = (gc >= 56) ? 1 : 0;
            half4 g4;
            g4[0] = (half_t)(s[0]*0.05f); g4[1] = (half_t)(s[1]*0.05f);
            g4[2] = (half_t)(s[2]*0.05f); g4[3] = (half_t)(s[3]*0.05f);
            *(half4*)(S + (2*ge+st)*SROW + 112 + (gc - st*56)) = g4;
        } else if (lane < 56) {
            // zero strip1 tail cols 156..167 (k-pad region gaf reads; cols
            // 160..167 are otherwise never initialized)
            const int u2 = lane - 50;               // 0..5
            const int le = (u2 >= 3) ? 1 : 0, lp = u2 - le*3;
            const half4 z4 = {};
            *(half4*)(S + (2*le+1)*SROW + 112 + 44 + lp*4) = z4;
        }
    }
    __builtin_amdgcn_s_barrier();
    // ---- gp = g @ aw0[100:]  (16-row tile; rows>=2 junk, discarded by guard)
    {
        half8 gaf[4][1];
        #pragma unroll
        for (int ks = 0; ks < 4; ++ks) {
            const int c = q*8 + ks*32;
            const int s = (c >= 112) ? 2 : (c >= 56 ? 1 : 0);
            gaf[ks][0] = *(const half8*)(S + (2*m + s)*SROW + 112 + (c - s*56));
        }
        run_layer<4,1,7,100,3,0,false>(gaf, S, wfL5, nullptr, gpb, lbufw, 0.f, lane);
    }
    __builtin_amdgcn_s_barrier();
    // ---- L2: fh = relu(h @ m2w0 + b)  (h from regs; cols 0..112 overwritten)
    run_layer<4,3,7,100,0,0,true>(hf, S, wfL2, m2b0, gpb, lbufw, 0.f, lane);
    __builtin_amdgcn_s_barrier();
    // ---- L3: f = fh @ m2w1 + b  -> cols 112..168 (f16, no relu)
    {
        half8 af[4][3]; load_af<4,3>(af, S, m, q);
        run_layer<4,3,4,50,1,0,false>(af, S, wfL3, m2b1, gpb, lbufw, 0.f, lane);
    }
    __builtin_amdgcn_s_barrier();
    // ---- L4: a1 = relu(h @ aw0[:100] + gp + ab0)  (h from regs; cols 0..112)
    run_layer<4,3,7,100,0,1,true>(hf, S, wfL4, ab0, gpb, lbufw, 0.f, lane);
    __builtin_amdgcn_s_barrier();
    // ---- L6: a2 = relu(a1 @ aw1 + ab1)  in-place
    {
        half8 af[4][3]; load_af<4,3>(af, S, m, q);
        run_layer<4,3,7,100,0,0,true>(af, S, wfL6, ab1, gpb, lbufw, 0.f, lane);
    }
    __builtin_amdgcn_s_barrier();
    // ---- L7: logits = a2 @ aw2 + ab2 -> lbufw
    {
        half8 af[4][3]; load_af<4,3>(af, S, m, q);
        run_layer<4,3,1,1,2,0,false>(af, S, wfL7, nullptr, gpb, lbufw, ab2[0], lane);
    }
    __builtin_amdgcn_s_barrier();
    // ---- weighted + self -> joint tile (rows 0..15, cols 0..64); vectorized
    {
        f32x4 wacc = {0.f,0.f,0.f,0.f};
        const int we = (lane >= 13) ? 1 : 0;
        const int wj = (lane - we*13) * 4;          // 0..48
        if (lane < 26) {
            #pragma unroll
            for (int n = 0; n < 20; ++n) {
                half4 f4 = *(const half4*)(S + (we*20+n)*SROW + 112 + wj);
                const float a = lbufw[we*20 + n];
                wacc[0] += (float)f4[0] * a;
                wacc[1] += (float)f4[1] * a;
                wacc[2] += (float)f4[2] * a;
                wacc[3] += (float)f4[3] * a;
            }
        }
        float sv = 0.f;
        const int su = lane - 32;
        const int se = (su >= 6) ? 1 : 0, sd = su - se*6;
        if (lane >= 32 && lane < 44)
            sv = state[(size_t)(ebase + se)*260 + sd];
        // zero joint tile rows 0..15 cols 0..63 (half8 = b128)
        const half8 z8 = {};
        #pragma unroll
        for (int z = 0; z < 2; ++z) {
            const int u = z*64 + lane;
            *(half8*)(S + (u >> 3)*SROW + (u & 7)*8) = z8;
        }
        if (lane < 26) {
            half2v p0, p1;
            p0[0] = (half_t)wacc[0]; p0[1] = (half_t)wacc[1];
            p1[0] = (half_t)wacc[2]; p1[1] = (half_t)wacc[3];
            *(half2v*)(S + we*SROW + 6 + wj) = p0;
            *(half2v*)(S + we*SROW + 6 + wj + 2) = p1;
        }
        if (lane >= 32 && lane < 44)
            S[se*SROW + sd] = (half_t)sv;
    }
    __builtin_amdgcn_s_barrier();
    // ---- head: v1 = relu(joint @ m3w0 + b0)  (rows 0..15, cols 0..160)
    {
        half8 af[2][1]; load_af<2,1>(af, S, m, q);
        run_layer<2,1,10,150,0,0,true>(af, S, wfL8, m3b0, gpb, lbufw, 0.f, lane);
    }
    __builtin_amdgcn_s_barrier();
    // ---- v2 = relu(v1 @ m3w1 + b1)
    {
        half8 af[5][1]; load_af<5,1>(af, S, m, q);
        run_layer<5,1,7,100,0,0,true>(af, S, wfL9, m3b1, gpb, lbufw, 0.f, lane);
    }
    __builtin_amdgcn_s_barrier();
    // ---- v3 = relu(v2 @ m3w2 + b2)
    {
        half8 af[4][1]; load_af<4,1>(af, S, m, q);
        run_layer<4,1,7,100,0,0,true>(af, S, wfL10, m3b2, gpb, lbufw, 0.f, lane);
    }
    // ---- out[e] = v3[e] . m3w3 + b3   (lanes 0-31 -> elem 0, 32-63 -> elem 1)
    {
        const int e = lane >> 5, k = lane & 31;
        const half_t* vr = S + e*SROW;
        float s = (float)vr[k]      * m3w3[k]
                + (float)vr[k + 32] * m3w3[k + 32]
                + (float)vr[k + 64] * m3w3[k + 64];
        if (k < 4) s += (float)vr[k + 96] * m3w3[k + 96];
        #pragma unroll
        for (int off = 16; off > 0; off >>= 1)
            s += __shfl_down(s, off, 32);
        if (k == 0) out[ebase + e] = s + m3b3[0];
    }
}

extern "C" void kernel_launch(void* const* d_in, const int* in_sizes, int n_in,
                              void* d_out, int out_size, void* d_ws, size_t ws_size,
                              hipStream_t stream) {
    const float* state = (const float*)d_in[0];
    const float* m1w0 = (const float*)d_in[1];
    const float* m1b0 = (const float*)d_in[2];
    const float* m1w1 = (const float*)d_in[3];
    const float* m1b1 = (const float*)d_in[4];
    const float* m2w0 = (const float*)d_in[5];
    const float* m2b0 = (const float*)d_in[6];
    const float* m2w1 = (const float*)d_in[7];
    const float* m2b1 = (const float*)d_in[8];
    const float* aw0  = (const float*)d_in[9];
    const float* ab0  = (const float*)d_in[10];
    const float* aw1  = (const float*)d_in[11];
    const float* ab1  = (const float*)d_in[12];
    const float* aw2  = (const float*)d_in[13];
    const float* ab2  = (const float*)d_in[14];
    const float* m3w0 = (const float*)d_in[15];
    const float* m3b0 = (const float*)d_in[16];
    const float* m3w1 = (const float*)d_in[17];
    const float* m3b1 = (const float*)d_in[18];
    const float* m3w2 = (const float*)d_in[19];
    const float* m3b2 = (const float*)d_in[20];
    const float* m3w3 = (const float*)d_in[21];
    const float* m3b3 = (const float*)d_in[22];

    half_t* wfrag = (half_t*)d_ws;   // 266 KB of fragments

    PrepArgs pa;
    int off = 0; size_t hoff = 0; int idx = 0;
    auto add = [&](const float* w, int K, int C, int KS, int NT) {
        pa.d[idx] = PrepDesc{w, wfrag + hoff, K, C, KS, NT, off};
        off += KS*NT;
        hoff += (size_t)KS*NT*512;
        ++idx;
    };
    add(m1w0, 13, 150, 1, 10);          // L0
    add(m1w1, 150, 100, 5, 7);          // L1
    add(m2w0, 100, 100, 4, 7);          // L2
    add(m2w1, 100, 50, 4, 4);           // L3
    add(aw0, 100, 100, 4, 7);           // L4 (rows 0..99)
    add(aw0 + 100*100, 100, 100, 4, 7); // L5 (rows 100..199)
    add(aw1, 100, 100, 4, 7);           // L6
    add(aw2, 100, 1, 4, 1);             // L7
    add(m3w0, 56, 150, 2, 10);          // L8
    add(m3w1, 150, 100, 5, 7);          // L9
    add(m3w2, 100, 100, 4, 7);          // L10

    k_prep<<<off, 64, 0, stream>>>(pa);

    k_main<<<NELEM/8, 256, 0, stream>>>(state, wfrag,
        m1b0, m1b1, m2b0, m2b1, ab0, ab1, ab2,
        m3b0, m3b1, m3b2, m3w3, m3b3, (float*)d_out);
}